// Round 9
// baseline (789.320 us; speedup 1.0000x reference)
//
#include <hip/hip_runtime.h>
#include <hip/hip_fp8.h>
#include <hip/hip_fp16.h>
#include <stdint.h>

#define FP8_MAX_V 448.0f

typedef float f32x16 __attribute__((ext_vector_type(16)));
typedef int i32x4 __attribute__((ext_vector_type(4)));
typedef int i32x8 __attribute__((ext_vector_type(8)));

__device__ __forceinline__ uint8_t cvt_fp8(float v) {
    return __hip_cvt_float_to_fp8(fminf(fmaxf(v, -FP8_MAX_V), FP8_MAX_V),
                                  __HIP_SATFINITE, __HIP_E4M3);
}

// ---------------- amax (per-tensor, exact) ----------------
__global__ void fp8lin_init(unsigned* amax_bits) {
    *amax_bits = 0u;
}

__global__ void fp8lin_amax(const float4* __restrict__ x, unsigned* __restrict__ amax_bits, long n4) {
    float m = 0.f;
    long stride = (long)gridDim.x * blockDim.x;
    for (long i = blockIdx.x * (long)blockDim.x + threadIdx.x; i < n4; i += stride) {
        float4 v = x[i];
        m = fmaxf(m, fmaxf(fmaxf(fabsf(v.x), fabsf(v.y)), fmaxf(fabsf(v.z), fabsf(v.w))));
    }
#pragma unroll
    for (int o = 32; o; o >>= 1) m = fmaxf(m, __shfl_xor(m, o));
    if ((threadIdx.x & 63) == 0) atomicMax(amax_bits, __float_as_uint(m));
}

// ---------------- derive scales ONCE ----------------
__global__ void fp8lin_scales(const unsigned* __restrict__ amax_bits,
                              const float* __restrict__ wscale,
                              float* __restrict__ scales) {
    float xs = fmaxf(__uint_as_float(*amax_bits), 1e-12f) / FP8_MAX_V;
    scales[0] = xs;
    scales[1] = xs * wscale[0];
}

// ---------------- probe weight transport dtype ----------------
__global__ void fp8lin_probe(const uint32_t* __restrict__ w, unsigned* __restrict__ flag) {
    __shared__ unsigned s32, s16, s4;
    if (threadIdx.x == 0) { s32 = 0u; s16 = 0u; s4 = 0u; }
    __syncthreads();
    unsigned o32 = 0u, o16 = 0u, o4 = 0u;
    for (int i = threadIdx.x; i < 4096; i += 256) {
        uint32_t v = w[i];
        o32 |= v & 0x000FFFFFu;
        uint32_t h0 = v & 0xFFFFu, h1 = v >> 16;
        o16 |= (h0 & 0x7Fu) | (h1 & 0x7Fu);
        o4  |= (h0 & 0x0Fu) | (h1 & 0x0Fu);
    }
    atomicOr(&s32, o32); atomicOr(&s16, o16); atomicOr(&s4, o4);
    __syncthreads();
    if (threadIdx.x == 0)
        *flag = (s32 == 0u) ? 0u : (s16 == 0u) ? 1u : (s4 == 0u) ? 2u : 3u;
}

// ---------------- convert transported weight -> raw fp8 (exact) ----------------
__global__ void fp8lin_convw(const void* __restrict__ wsrc, const unsigned* __restrict__ flag,
                             uchar4* __restrict__ wq, long n4) {
    unsigned f = *flag;
    if (f == 3u) return;
    long stride = (long)gridDim.x * blockDim.x;
    if (f == 0u) {
        const float4* src = (const float4*)wsrc;
        for (long i = blockIdx.x * (long)blockDim.x + threadIdx.x; i < n4; i += stride) {
            float4 v = src[i];
            uchar4 o;
            o.x = cvt_fp8(v.x); o.y = cvt_fp8(v.y); o.z = cvt_fp8(v.z); o.w = cvt_fp8(v.w);
            wq[i] = o;
        }
    } else if (f == 1u) {
        const __half2* src = (const __half2*)wsrc;
        for (long i = blockIdx.x * (long)blockDim.x + threadIdx.x; i < n4; i += stride) {
            __half2 v0 = src[2 * i], v1 = src[2 * i + 1];
            uchar4 o;
            o.x = cvt_fp8(__half2float(v0.x)); o.y = cvt_fp8(__half2float(v0.y));
            o.z = cvt_fp8(__half2float(v1.x)); o.w = cvt_fp8(__half2float(v1.y));
            wq[i] = o;
        }
    } else {
        const ushort2* src = (const ushort2*)wsrc;
        for (long i = blockIdx.x * (long)blockDim.x + threadIdx.x; i < n4; i += stride) {
            ushort2 v0 = src[2 * i], v1 = src[2 * i + 1];
            uchar4 o;
            o.x = cvt_fp8(__uint_as_float((uint32_t)v0.x << 16));
            o.y = cvt_fp8(__uint_as_float((uint32_t)v0.y << 16));
            o.z = cvt_fp8(__uint_as_float((uint32_t)v1.x << 16));
            o.w = cvt_fp8(__uint_as_float((uint32_t)v1.y << 16));
            wq[i] = o;
        }
    }
}

// ---------------- quantize x -> fp8 e4m3fn ----------------
__global__ void fp8lin_quant(const float4* __restrict__ x, const float* __restrict__ scales,
                             uchar4* __restrict__ xq, long n4) {
    float s = scales[0];
    long stride = (long)gridDim.x * blockDim.x;
    for (long i = blockIdx.x * (long)blockDim.x + threadIdx.x; i < n4; i += stride) {
        float4 v = x[i];
        uchar4 o;
        o.x = cvt_fp8(v.x / s); o.y = cvt_fp8(v.y / s);
        o.z = cvt_fp8(v.z / s); o.w = cvt_fp8(v.w / s);
        xq[i] = o;
    }
}

// ---- fp8 GEMM: 256x256, BK=64, 8 waves, MX 32x32x64, tri-buffer, 4-phase/K-tile ----
#define BM 256
#define BN 256
#define BK 64
#define A_TILE 16384                  // 256 rows x 64 B
#define B_TILE 16384
#define BUF_BYTES (A_TILE + B_TILE)   // 32 KiB
#define SMEM_BYTES (3 * BUF_BYTES)    // 96 KiB tri-buffered

__device__ __forceinline__ void gload16(const uint8_t* src, uint8_t* ldst) {
    __builtin_amdgcn_global_load_lds(
        (const __attribute__((address_space(1))) uint32_t*)(uintptr_t)src,
        (__attribute__((address_space(3))) uint32_t*)(uintptr_t)ldst, 16, 0, 0);
}

#define WAITVM(N) asm volatile("s_waitcnt vmcnt(" #N ")" ::: "memory")
#define LGKM0() do { asm volatile("s_waitcnt lgkmcnt(0)" ::: "memory"); \
                     __builtin_amdgcn_sched_barrier(0); } while (0)
#define BARRIER() do { asm volatile("" ::: "memory"); __builtin_amdgcn_s_barrier(); \
                       asm volatile("" ::: "memory"); } while (0)

// load one 32B k-fragment (two ds_read_b128 at XOR-16 swizzled granules)
#define LDFRAG(dst, base, off) do {                                    \
    i32x4 _lo = *(const i32x4*)((base) + (off));                       \
    i32x4 _hi = *(const i32x4*)((base) + ((off) ^ 16));                \
    dst[0] = _lo[0]; dst[1] = _lo[1]; dst[2] = _lo[2]; dst[3] = _lo[3];\
    dst[4] = _hi[0]; dst[5] = _hi[1]; dst[6] = _hi[2]; dst[7] = _hi[3];\
} while (0)

// unit scales: e8m0 byte 0x7f = 2^0, every byte identical so opsel-immune
#define MFMA_MX(A, B, C) __builtin_amdgcn_mfma_scale_f32_32x32x64_f8f6f4( \
    (A), (B), (C), 0, 0, 0, (int)0x7f7f7f7f, 0, (int)0x7f7f7f7f)

// min-waves/EU = 2 (256-reg budget). Forcing 4 spilled the 128-reg acc (R6).
__global__ __launch_bounds__(512, 2) void fp8lin_gemm(
    const uint8_t* __restrict__ Aq,    // [M,K] fp8
    const uint8_t* __restrict__ Wraw,  // original weight ptr (valid iff flag==3)
    const uint8_t* __restrict__ Wconv, // converted fp8 (valid iff flag!=3)
    const unsigned* __restrict__ flag,
    const float* __restrict__ scales,
    const float* __restrict__ bias,
    float* __restrict__ out,
    int M, int N, int K) {
    extern __shared__ __align__(16) uint8_t smem[];

    const uint8_t* __restrict__ Wq = (*flag == 3u) ? Wraw : Wconv;

    const int tid = threadIdx.x;
    const int wid = tid >> 6;
    const int lane = tid & 63;
    const int wm = wid >> 2;   // 0..1  (M-wave, 128 rows each)
    const int wn = wid & 3;    // 0..3  (N-wave, 64 cols each)

    // ---- bijective XCD swizzle ----
    const int nbx = gridDim.x;                       // 64
    const int orig = blockIdx.y * nbx + blockIdx.x;
    const int cpx = (gridDim.x * gridDim.y) >> 3;    // 256
    const int swzb = (orig & 7) * cpx + (orig >> 3);
    const int brow = (swzb / nbx) * BM;
    const int bcol = (swzb % nbx) * BN;

    // ---- staging: wave w owns A chunks {2w,2w+1} and B chunks {2w,2w+1} (1KB each)
    // LDS granule p of row r holds global granule p ^ ((r>>1)&3) (pre-swizzled src)
    const int ca0 = wid * 2, ca1 = wid * 2 + 1;
    const int rA0 = ca0 * 16 + (lane >> 2), rA1 = ca1 * 16 + (lane >> 2);
    const int gA0 = ((lane & 3) ^ ((rA0 >> 1) & 3)) * 16;
    const int gA1 = ((lane & 3) ^ ((rA1 >> 1) & 3)) * 16;
    const uint8_t* sA0 = Aq + (size_t)(brow + rA0) * K + gA0;
    const uint8_t* sA1 = Aq + (size_t)(brow + rA1) * K + gA1;
    const uint8_t* sB0 = Wq + (size_t)(bcol + rA0) * K + gA0;
    const uint8_t* sB1 = Wq + (size_t)(bcol + rA1) * K + gA1;
    const int dA0 = ca0 * 1024, dA1 = ca1 * 1024;            // wave-uniform LDS bases
    const int dB0 = A_TILE + ca0 * 1024, dB1 = A_TILE + ca1 * 1024;

    // ---- ds_read addressing ----
    const int l31 = lane & 31;
    const int q = lane >> 5;
    const int swzr = (l31 >> 1) & 3;          // row-base is mult of 32
    const int posl = (2 * q) ^ swzr;
    const int offA = (wm * 128 + l31) * 64 + posl * 16;  // + mi*2048
    const int offB = (wn * 64 + l31) * 64 + posl * 16;   // + ni*2048

    f32x16 acc[4][2];
#pragma unroll
    for (int mi = 0; mi < 4; ++mi)
#pragma unroll
        for (int ni = 0; ni < 2; ++ni)
#pragma unroll
            for (int r = 0; r < 16; ++r) acc[mi][ni][r] = 0.0f;

    // ---- prologue: stage tiles 0 and 1; counted wait so tile 1 stays in flight
    {
        uint8_t* b0 = smem;
        uint8_t* b1 = smem + BUF_BYTES;
        gload16(sA0, b0 + dA0); gload16(sA1, b0 + dA1);
        gload16(sB0, b0 + dB0); gload16(sB1, b0 + dB1);
        gload16(sA0 + BK, b1 + dA0); gload16(sA1 + BK, b1 + dA1);
        gload16(sB0 + BK, b1 + dB0); gload16(sB1 + BK, b1 + dB1);
        WAITVM(4);
        BARRIER();
    }

    const int NT = K / BK;  // 64
    int cur = 0;
    for (int t = 0; t < NT; ++t) {
        const uint8_t* bA = smem + cur * BUF_BYTES;
        const uint8_t* bB = bA + A_TILE;
        int nxt = cur + 2; if (nxt >= 3) nxt -= 3;
        uint8_t* nb = smem + nxt * BUF_BYTES;
        const bool st = (t + 2) < NT;
        const size_t k2 = (size_t)(t + 2) * BK;

        i32x8 a0, a1, a2, a3, b0, b1;
        // ---- P0: reads a0,a1,b0 | stage A0 | mfma m{0,1}n0
        LDFRAG(a0, bA, offA);
        LDFRAG(a1, bA, offA + 2048);
        LDFRAG(b0, bB, offB);
        if (st) gload16(sA0 + k2, nb + dA0);
        BARRIER();
        LGKM0();
        __builtin_amdgcn_s_setprio(1);
        acc[0][0] = MFMA_MX(a0, b0, acc[0][0]);
        acc[1][0] = MFMA_MX(a1, b0, acc[1][0]);
        __builtin_amdgcn_s_setprio(0);
        BARRIER();
        // ---- P1: reads b1 | stage A1 | mfma m{0,1}n1
        LDFRAG(b1, bB, offB + 2048);
        if (st) gload16(sA1 + k2, nb + dA1);
        BARRIER();
        LGKM0();
        __builtin_amdgcn_s_setprio(1);
        acc[0][1] = MFMA_MX(a0, b1, acc[0][1]);
        acc[1][1] = MFMA_MX(a1, b1, acc[1][1]);
        __builtin_amdgcn_s_setprio(0);
        BARRIER();
        // ---- P2: reads a2,a3 | stage B0 | mfma m{2,3}n0
        LDFRAG(a2, bA, offA + 4096);
        LDFRAG(a3, bA, offA + 6144);
        if (st) gload16(sB0 + k2, nb + dB0);
        BARRIER();
        LGKM0();
        __builtin_amdgcn_s_setprio(1);
        acc[2][0] = MFMA_MX(a2, b0, acc[2][0]);
        acc[3][0] = MFMA_MX(a3, b0, acc[3][0]);
        __builtin_amdgcn_s_setprio(0);
        BARRIER();
        // ---- P3: stage B1 | mfma m{2,3}n1 | counted vmcnt once per tile
        if (st) gload16(sB1 + k2, nb + dB1);
        BARRIER();
        LGKM0();
        __builtin_amdgcn_s_setprio(1);
        acc[2][1] = MFMA_MX(a2, b1, acc[2][1]);
        acc[3][1] = MFMA_MX(a3, b1, acc[3][1]);
        __builtin_amdgcn_s_setprio(0);
        if (t < NT - 2) { WAITVM(4); }          // next tile's 4 landed; t+2's in flight
        else if (t == NT - 2) { WAITVM(0); }    // drain for the last tile
        BARRIER();
        ++cur; if (cur == 3) cur = 0;
    }

    // ---- epilogue: 32x32 C/D layout col=lane&31, row=(reg&3)+8*(reg>>2)+4*q ----
    float s = scales[1];
    const int colg = bcol + wn * 64 + l31;
    const int rowg0 = brow + wm * 128 + 4 * q;
#pragma unroll
    for (int ni = 0; ni < 2; ++ni) {
        int col = colg + ni * 32;
        float bv = bias[col];
#pragma unroll
        for (int mi = 0; mi < 4; ++mi) {
            int rb = rowg0 + mi * 32;
#pragma unroll
            for (int reg = 0; reg < 16; ++reg) {
                int row = rb + (reg & 3) + 8 * (reg >> 2);
                __builtin_nontemporal_store(acc[mi][ni][reg] * s + bv,
                                            out + (size_t)row * N + col);
            }
        }
    }
}

extern "C" void kernel_launch(void* const* d_in, const int* in_sizes, int n_in,
                              void* d_out, int out_size, void* d_ws, size_t ws_size,
                              hipStream_t stream) {
    const float* x = (const float*)d_in[0];
    const void* w = d_in[1];
    const float* wscale = (const float*)d_in[2];
    const float* bias = (const float*)d_in[3];
    float* out = (float*)d_out;

    const int Bb = 4, S = 2048, K = 4096, N = 16384;
    const int M = Bb * S;
    const long nx = (long)M * K;
    const long nw = (long)N * K;

    unsigned* amax_bits = (unsigned*)d_ws;
    float* scales = (float*)((char*)d_ws + 16);
    unsigned* wflag = (unsigned*)((char*)d_ws + 32);
    uchar4* xq = (uchar4*)((char*)d_ws + 256);
    uchar4* wq = (uchar4*)((char*)d_ws + 256 + nx);

    fp8lin_init<<<1, 1, 0, stream>>>(amax_bits);
    fp8lin_probe<<<1, 256, 0, stream>>>((const uint32_t*)w, wflag);
    fp8lin_amax<<<2048, 256, 0, stream>>>((const float4*)x, amax_bits, nx / 4);
    fp8lin_scales<<<1, 1, 0, stream>>>(amax_bits, wscale, scales);
    fp8lin_quant<<<2048, 256, 0, stream>>>((const float4*)x, scales, xq, nx / 4);
    fp8lin_convw<<<2048, 256, 0, stream>>>(w, wflag, wq, nw / 4);

    dim3 grid(N / BN, M / BM);   // (64, 32) = 2048 blocks
    fp8lin_gemm<<<grid, 512, SMEM_BYTES, stream>>>((const uint8_t*)xq, (const uint8_t*)w,
                                                   (const uint8_t*)wq, wflag, scales, bias, out,
                                                   M, N, K);
}